// Round 11
// baseline (77.515 us; speedup 1.0000x reference)
//
#include <hip/hip_runtime.h>

#define DM    1024
#define NTOK  32768   // B*S
#define NRED  16384
#define NSAVE 16384
#define MMAX  16384   // max compacted rows

typedef __attribute__((ext_vector_type(8))) short bf16x8;
typedef __attribute__((ext_vector_type(4))) float f32x4;

__device__ __forceinline__ ushort f2bf(float f) {
    union { float f; unsigned u; } v; v.f = f;
    unsigned r = (v.u + 0x7FFF + ((v.u >> 16) & 1)) >> 16;   // RNE
    return (ushort)r;
}
__device__ __forceinline__ float bf2f(ushort u) {
    union { unsigned u; float f; } v; v.u = ((unsigned)u) << 16;
    return v.f;
}

// ---------------------------------------------------------------------------
__global__ __launch_bounds__(256) void setup_kernel(const float* __restrict__ W,
                                                    ushort* __restrict__ Wb,
                                                    int* __restrict__ cnt,
                                                    int* __restrict__ need,
                                                    int* __restrict__ counter) {
    int t = blockIdx.x * 256 + threadIdx.x;
    float4 v = ((const float4*)W)[t];
    ushort4 o;
    o.x = f2bf(v.x); o.y = f2bf(v.y); o.z = f2bf(v.z); o.w = f2bf(v.w);
    ((ushort4*)Wb)[t] = o;
    if (t < NTOK) { cnt[t] = 0; need[t] = 0; }
    if (t == 0) *counter = 0;
}

// ---------------------------------------------------------------------------
__global__ __launch_bounds__(256) void prep_kernel(const int* __restrict__ red,
                                                   const int* __restrict__ sav,
                                                   int* __restrict__ cnt,
                                                   int* __restrict__ need) {
    int j = blockIdx.x * 256 + threadIdx.x;
    if (j >= NRED) return;
    atomicAdd(&cnt[red[j]], 1);
    int s = sav[j];
    if (s > 0) need[s - 1] = 1;
}

// ---------------------------------------------------------------------------
__global__ __launch_bounds__(256) void compact_kernel(const int* __restrict__ cnt,
                                                      const int* __restrict__ need,
                                                      int* __restrict__ inv,
                                                      int* __restrict__ list,
                                                      int* __restrict__ counter) {
    int t = blockIdx.x * 256 + threadIdx.x;
    if (t >= NTOK) return;
    if (need[t] && cnt[t] > 0) {
        int pos = atomicAdd(counter, 1);
        inv[t] = pos;
        list[pos] = t;
    }
}

// ---------------------------------------------------------------------------
// convx: gather + fp32->bf16 convert compacted rows; zero-pad to 128 multiple
// ---------------------------------------------------------------------------
__global__ __launch_bounds__(256) void convx_kernel(const float* __restrict__ X,
                                                    const int* __restrict__ list,
                                                    const int* __restrict__ counter,
                                                    ushort* __restrict__ Xb) {
    const int M = *counter;
    const int Mpad = (M + 127) & ~127;
    for (int r = blockIdx.x; r < Mpad; r += gridDim.x) {
        ushort4 o;
        if (r < M) {
            int src = list[r];
            float4 v = ((const float4*)(X + (size_t)src * DM))[threadIdx.x];
            o.x = f2bf(v.x); o.y = f2bf(v.y); o.z = f2bf(v.z); o.w = f2bf(v.w);
        } else {
            o.x = 0; o.y = 0; o.z = 0; o.w = 0;
        }
        ((ushort4*)(Xb + (size_t)r * DM))[threadIdx.x] = o;
    }
}

// ---------------------------------------------------------------------------
// bf16 MFMA GEMM, depth-2 pipelined: Tb[m,n] = bf16( sum_k Xb[m,k]*Wb[n,k] )
// BM=BN=128, BK=32, 4 waves; wave w owns m-rows [w*32,w*32+32) x all 128 n
// (2x8 frags of 16x16x32, 16 MFMA/step, acc 64 VGPR). THREE 16 KB LDS bufs
// (48 KB -> 3 wg/CU = 12 waves/CU): step t computes buf[t%3], stages
// buf[(t+2)%3], waits vmcnt(8) -> consumed loads were issued TWO compute
// phases ago (depth-2 latency tolerance; R9 post-mortem: latency, not LDS
// pipe, binds this shape). BK=32 rows are 64 B, so each fragment read is a
// contiguous 1 KB wave read -> zero bank conflicts, no swizzle, and staging
// is plain linear global_load_lds(16). setprio(1) around MFMA (T5: 3
// independent wgs/CU = phase-diverse). 2 barriers/step as in R7 (validated).
// ---------------------------------------------------------------------------
__global__ __launch_bounds__(256) void gemm_kernel(const ushort* __restrict__ Xb,
                                                   const ushort* __restrict__ Wb,
                                                   const int* __restrict__ counter,
                                                   ushort* __restrict__ Tb) {
    const int M = *counter;
    const int m0 = blockIdx.x * 128;
    if (m0 >= M) return;                 // uniform exit before any barrier
    const int n0 = blockIdx.y * 128;

    __shared__ char lds[49152];          // 3 bufs x (A 8KB + B 8KB)

    const int tid = threadIdx.x;
    const int l   = tid & 63;
    const int w   = tid >> 6;            // 0..3

    // staging: wave w covers rows [w*32, w*32+32) of A and of B; instr i
    // covers 16 rows; lane: row = w*32 + i*16 + (l>>2), 16B chunk c = l&3.
    const int srow = l >> 2;             // 0..15
    const int sc   = l & 3;
    const ushort* aS = Xb + (size_t)(m0 + w * 32 + srow) * DM + sc * 8;
    const ushort* bS = Wb + (size_t)(n0 + w * 32 + srow) * DM + sc * 8;
    const int dOff = w * 2048;           // byte offset of wave's 32-row band

#define STAGE(buf, kstep) do {                                                        \
    char* _d = lds + (buf) * 16384 + dOff;                                            \
    const int _k = (kstep) * 32;                                                      \
    __builtin_amdgcn_global_load_lds(                                                 \
        (const __attribute__((address_space(1))) unsigned*)(aS + _k),                 \
        (__attribute__((address_space(3))) unsigned*)(_d), 16, 0, 0);                 \
    __builtin_amdgcn_global_load_lds(                                                 \
        (const __attribute__((address_space(1))) unsigned*)(aS + _k + 16 * DM),       \
        (__attribute__((address_space(3))) unsigned*)(_d + 1024), 16, 0, 0);          \
    __builtin_amdgcn_global_load_lds(                                                 \
        (const __attribute__((address_space(1))) unsigned*)(bS + _k),                 \
        (__attribute__((address_space(3))) unsigned*)(_d + 8192), 16, 0, 0);          \
    __builtin_amdgcn_global_load_lds(                                                 \
        (const __attribute__((address_space(1))) unsigned*)(bS + _k + 16 * DM),       \
        (__attribute__((address_space(3))) unsigned*)(_d + 8192 + 1024), 16, 0, 0);   \
} while (0)

    // fragment read byte-offsets within a buffer (LDS rows 64 B, linear)
    const int kgrp = l >> 4;
    const int r16  = l & 15;
    int aoff[2], boff[8];
#pragma unroll
    for (int fm = 0; fm < 2; ++fm)
        aoff[fm] = (w * 32 + fm * 16 + r16) * 64 + kgrp * 16;
#pragma unroll
    for (int fn = 0; fn < 8; ++fn)
        boff[fn] = 8192 + (fn * 16 + r16) * 64 + kgrp * 16;

    f32x4 acc[2][8] = {};

    STAGE(0, 0);
    STAGE(1, 1);
#pragma unroll
    for (int t = 0; t < 32; ++t) {
        const char* base = lds + (t % 3) * 16384;
        if (t < 30) {
            STAGE((t + 2) % 3, t + 2);
            asm volatile("s_waitcnt vmcnt(8)" ::: "memory");   // buf[t%3]'s loads landed (mine)
        } else if (t == 30) {
            asm volatile("s_waitcnt vmcnt(4)" ::: "memory");
        } else {
            asm volatile("s_waitcnt vmcnt(0)" ::: "memory");
        }
        __builtin_amdgcn_sched_barrier(0);
        __builtin_amdgcn_s_barrier();                          // landed for ALL waves

        bf16x8 af[2], bfr[8];
#pragma unroll
        for (int fm = 0; fm < 2; ++fm) af[fm]  = *(const bf16x8*)(base + aoff[fm]);
#pragma unroll
        for (int fn = 0; fn < 8; ++fn) bfr[fn] = *(const bf16x8*)(base + boff[fn]);
        __builtin_amdgcn_s_setprio(1);
#pragma unroll
        for (int fm = 0; fm < 2; ++fm)
#pragma unroll
            for (int fn = 0; fn < 8; ++fn)
                acc[fm][fn] = __builtin_amdgcn_mfma_f32_16x16x32_bf16(af[fm], bfr[fn], acc[fm][fn], 0, 0, 0);
        __builtin_amdgcn_s_setprio(0);

        if (t < 31)
            __builtin_amdgcn_s_barrier();   // all reads of buf[t%3] done; t+1 may overwrite it
    }
#undef STAGE

    // C/D layout: col = lane&15, row = (lane>>4)*4 + reg  [m89]
#pragma unroll
    for (int fm = 0; fm < 2; ++fm) {
        int mbase = m0 + w * 32 + fm * 16 + kgrp * 4;
#pragma unroll
        for (int fn = 0; fn < 8; ++fn) {
            int n = n0 + fn * 16 + r16;
#pragma unroll
            for (int r = 0; r < 4; ++r) {
                int m = mbase + r;
                if (m < M) Tb[(size_t)m * DM + n] = f2bf(acc[fm][fn][r]);
            }
        }
    }
}

// ---------------------------------------------------------------------------
// epilogue: out[r] = x[s] + cnt[s-1] * Tb[inv[s-1]]
// ---------------------------------------------------------------------------
__global__ __launch_bounds__(256) void out_kernel(const float* __restrict__ X,
                                                  const ushort* __restrict__ Tb,
                                                  const int* __restrict__ sav,
                                                  const int* __restrict__ cnt,
                                                  const int* __restrict__ inv,
                                                  float* __restrict__ out) {
    int r = blockIdx.x;
    int d = threadIdx.x;                 // float4 lane, 0..255
    int s = sav[r];
    const float4* xr = (const float4*)(X + (size_t)s * DM);
    float4 v = xr[d];
    if (s > 0) {
        int t = s - 1;
        int c = cnt[t];
        if (c > 0) {
            float fc = (float)c;
            const ushort4* tr = (const ushort4*)(Tb + (size_t)inv[t] * DM);
            ushort4 wv = tr[d];
            v.x += fc * bf2f(wv.x); v.y += fc * bf2f(wv.y);
            v.z += fc * bf2f(wv.z); v.w += fc * bf2f(wv.w);
        }
    }
    ((float4*)out)[(size_t)r * (DM / 4) + d] = v;
}

// ---------------------------------------------------------------------------
extern "C" void kernel_launch(void* const* d_in, const int* in_sizes, int n_in,
                              void* d_out, int out_size, void* d_ws, size_t ws_size,
                              hipStream_t stream) {
    const float* X   = (const float*)d_in[0];
    const float* W   = (const float*)d_in[1];
    const int*   sav = (const int*)d_in[2];   // ids_to_save
    const int*   red = (const int*)d_in[3];   // ids_to_reduce
    float* out = (float*)d_out;

    char* ws = (char*)d_ws;
    int* counter = (int*)ws;                  // 64 ints
    int* cnt  = counter + 64;                 // 32768
    int* need = cnt + NTOK;                   // 32768
    int* inv  = need + NTOK;                  // 32768
    int* list = inv + NTOK;                   // 16384  (ends < 512 KB)
    ushort* Wb = (ushort*)(ws + (1 << 19));   // 2 MB bf16 W
    ushort* Xb = (ushort*)(ws + (4 << 20));   // 32 MB bf16 compacted X rows (padded)
    ushort* Tb = (ushort*)(ws + (36u << 20)); // 32 MB bf16 T

    setup_kernel<<<DM * DM / 4 / 256, 256, 0, stream>>>(W, Wb, cnt, need, counter);
    prep_kernel<<<NRED / 256, 256, 0, stream>>>(red, sav, cnt, need);
    compact_kernel<<<NTOK / 256, 256, 0, stream>>>(cnt, need, inv, list, counter);
    convx_kernel<<<2048, 256, 0, stream>>>(X, list, counter, Xb);

    dim3 ggrid(MMAX / 128, DM / 128);         // x = m-blocks (128, early-exit), y = n (8)
    gemm_kernel<<<ggrid, 256, 0, stream>>>(Xb, Wb, counter, Tb);

    out_kernel<<<NSAVE, 256, 0, stream>>>(X, Tb, sav, cnt, inv, out);
}

// Round 12
// 77.078 us; speedup vs baseline: 1.0057x; 1.0057x over previous
//
#include <hip/hip_runtime.h>

#define DM    1024
#define NTOK  32768   // B*S
#define NRED  16384
#define NSAVE 16384
#define MMAX  16384   // max compacted rows

typedef __attribute__((ext_vector_type(8))) short bf16x8;
typedef __attribute__((ext_vector_type(4))) float f32x4;

__device__ __forceinline__ ushort f2bf(float f) {
    union { float f; unsigned u; } v; v.f = f;
    unsigned r = (v.u + 0x7FFF + ((v.u >> 16) & 1)) >> 16;   // RNE
    return (ushort)r;
}
__device__ __forceinline__ float bf2f(ushort u) {
    union { unsigned u; float f; } v; v.u = ((unsigned)u) << 16;
    return v.f;
}

// ---------------------------------------------------------------------------
__global__ __launch_bounds__(256) void setup_kernel(const float* __restrict__ W,
                                                    ushort* __restrict__ Wb,
                                                    int* __restrict__ cnt,
                                                    int* __restrict__ need,
                                                    int* __restrict__ counter) {
    int t = blockIdx.x * 256 + threadIdx.x;
    float4 v = ((const float4*)W)[t];
    ushort4 o;
    o.x = f2bf(v.x); o.y = f2bf(v.y); o.z = f2bf(v.z); o.w = f2bf(v.w);
    ((ushort4*)Wb)[t] = o;
    if (t < NTOK) { cnt[t] = 0; need[t] = 0; }
    if (t == 0) *counter = 0;
}

// ---------------------------------------------------------------------------
__global__ __launch_bounds__(256) void prep_kernel(const int* __restrict__ red,
                                                   const int* __restrict__ sav,
                                                   int* __restrict__ cnt,
                                                   int* __restrict__ need) {
    int j = blockIdx.x * 256 + threadIdx.x;
    if (j >= NRED) return;
    atomicAdd(&cnt[red[j]], 1);
    int s = sav[j];
    if (s > 0) need[s - 1] = 1;
}

// ---------------------------------------------------------------------------
__global__ __launch_bounds__(256) void compact_kernel(const int* __restrict__ cnt,
                                                      const int* __restrict__ need,
                                                      int* __restrict__ inv,
                                                      int* __restrict__ list,
                                                      int* __restrict__ counter) {
    int t = blockIdx.x * 256 + threadIdx.x;
    if (t >= NTOK) return;
    if (need[t] && cnt[t] > 0) {
        int pos = atomicAdd(counter, 1);
        inv[t] = pos;
        list[pos] = t;
    }
}

// ---------------------------------------------------------------------------
// convx: gather + fp32->bf16 convert compacted rows; zero-pad to 128 multiple
// ---------------------------------------------------------------------------
__global__ __launch_bounds__(256) void convx_kernel(const float* __restrict__ X,
                                                    const int* __restrict__ list,
                                                    const int* __restrict__ counter,
                                                    ushort* __restrict__ Xb) {
    const int M = *counter;
    const int Mpad = (M + 127) & ~127;
    for (int r = blockIdx.x; r < Mpad; r += gridDim.x) {
        ushort4 o;
        if (r < M) {
            int src = list[r];
            float4 v = ((const float4*)(X + (size_t)src * DM))[threadIdx.x];
            o.x = f2bf(v.x); o.y = f2bf(v.y); o.z = f2bf(v.z); o.w = f2bf(v.w);
        } else {
            o.x = 0; o.y = 0; o.z = 0; o.w = 0;
        }
        ((ushort4*)(Xb + (size_t)r * DM))[threadIdx.x] = o;
    }
}

// ---------------------------------------------------------------------------
// bf16 MFMA GEMM, depth-2 pipelined: Tb[m,n] = bf16( sum_k Xb[m,k]*Wb[n,k] )
// BM=BN=128, BK=32, 4 waves; wave w owns m-rows [w*32,w*32+32) x all 128 n
// (2x8 frags of 16x16x32, 16 MFMA/step, acc 64 VGPR). THREE 16 KB LDS bufs
// (48 KB -> 3 wg/CU = 12 waves/CU): step t computes buf[t%3], stages
// buf[(t+2)%3], waits vmcnt(8) -> consumed loads were issued TWO compute
// phases ago (depth-2 latency tolerance; R9 post-mortem: latency, not LDS
// pipe, binds this shape). BK=32 rows are 64 B, so each fragment read is a
// contiguous 1 KB wave read -> zero bank conflicts, no swizzle, and staging
// is plain linear global_load_lds(16). setprio(1) around MFMA (T5: 3
// independent wgs/CU = phase-diverse). 2 barriers/step as in R7 (validated).
// ---------------------------------------------------------------------------
__global__ __launch_bounds__(256) void gemm_kernel(const ushort* __restrict__ Xb,
                                                   const ushort* __restrict__ Wb,
                                                   const int* __restrict__ counter,
                                                   ushort* __restrict__ Tb) {
    const int M = *counter;
    const int m0 = blockIdx.x * 128;
    if (m0 >= M) return;                 // uniform exit before any barrier
    const int n0 = blockIdx.y * 128;

    __shared__ char lds[49152];          // 3 bufs x (A 8KB + B 8KB)

    const int tid = threadIdx.x;
    const int l   = tid & 63;
    const int w   = tid >> 6;            // 0..3

    // staging: wave w covers rows [w*32, w*32+32) of A and of B; instr i
    // covers 16 rows; lane: row = w*32 + i*16 + (l>>2), 16B chunk c = l&3.
    const int srow = l >> 2;             // 0..15
    const int sc   = l & 3;
    const ushort* aS = Xb + (size_t)(m0 + w * 32 + srow) * DM + sc * 8;
    const ushort* bS = Wb + (size_t)(n0 + w * 32 + srow) * DM + sc * 8;
    const int dOff = w * 2048;           // byte offset of wave's 32-row band

#define STAGE(buf, kstep) do {                                                        \
    char* _d = lds + (buf) * 16384 + dOff;                                            \
    const int _k = (kstep) * 32;                                                      \
    __builtin_amdgcn_global_load_lds(                                                 \
        (const __attribute__((address_space(1))) unsigned*)(aS + _k),                 \
        (__attribute__((address_space(3))) unsigned*)(_d), 16, 0, 0);                 \
    __builtin_amdgcn_global_load_lds(                                                 \
        (const __attribute__((address_space(1))) unsigned*)(aS + _k + 16 * DM),       \
        (__attribute__((address_space(3))) unsigned*)(_d + 1024), 16, 0, 0);          \
    __builtin_amdgcn_global_load_lds(                                                 \
        (const __attribute__((address_space(1))) unsigned*)(bS + _k),                 \
        (__attribute__((address_space(3))) unsigned*)(_d + 8192), 16, 0, 0);          \
    __builtin_amdgcn_global_load_lds(                                                 \
        (const __attribute__((address_space(1))) unsigned*)(bS + _k + 16 * DM),       \
        (__attribute__((address_space(3))) unsigned*)(_d + 8192 + 1024), 16, 0, 0);   \
} while (0)

    // fragment read byte-offsets within a buffer (LDS rows 64 B, linear)
    const int kgrp = l >> 4;
    const int r16  = l & 15;
    int aoff[2], boff[8];
#pragma unroll
    for (int fm = 0; fm < 2; ++fm)
        aoff[fm] = (w * 32 + fm * 16 + r16) * 64 + kgrp * 16;
#pragma unroll
    for (int fn = 0; fn < 8; ++fn)
        boff[fn] = 8192 + (fn * 16 + r16) * 64 + kgrp * 16;

    f32x4 acc[2][8] = {};

    STAGE(0, 0);
    STAGE(1, 1);
#pragma unroll
    for (int t = 0; t < 32; ++t) {
        const char* base = lds + (t % 3) * 16384;
        if (t < 30) {
            STAGE((t + 2) % 3, t + 2);
            asm volatile("s_waitcnt vmcnt(8)" ::: "memory");   // buf[t%3]'s loads landed (mine)
        } else if (t == 30) {
            asm volatile("s_waitcnt vmcnt(4)" ::: "memory");
        } else {
            asm volatile("s_waitcnt vmcnt(0)" ::: "memory");
        }
        __builtin_amdgcn_sched_barrier(0);
        __builtin_amdgcn_s_barrier();                          // landed for ALL waves

        bf16x8 af[2], bfr[8];
#pragma unroll
        for (int fm = 0; fm < 2; ++fm) af[fm]  = *(const bf16x8*)(base + aoff[fm]);
#pragma unroll
        for (int fn = 0; fn < 8; ++fn) bfr[fn] = *(const bf16x8*)(base + boff[fn]);
        __builtin_amdgcn_s_setprio(1);
#pragma unroll
        for (int fm = 0; fm < 2; ++fm)
#pragma unroll
            for (int fn = 0; fn < 8; ++fn)
                acc[fm][fn] = __builtin_amdgcn_mfma_f32_16x16x32_bf16(af[fm], bfr[fn], acc[fm][fn], 0, 0, 0);
        __builtin_amdgcn_s_setprio(0);

        if (t < 31)
            __builtin_amdgcn_s_barrier();   // all reads of buf[t%3] done; t+1 may overwrite it
    }
#undef STAGE

    // C/D layout: col = lane&15, row = (lane>>4)*4 + reg  [m89]
#pragma unroll
    for (int fm = 0; fm < 2; ++fm) {
        int mbase = m0 + w * 32 + fm * 16 + kgrp * 4;
#pragma unroll
        for (int fn = 0; fn < 8; ++fn) {
            int n = n0 + fn * 16 + r16;
#pragma unroll
            for (int r = 0; r < 4; ++r) {
                int m = mbase + r;
                if (m < M) Tb[(size_t)m * DM + n] = f2bf(acc[fm][fn][r]);
            }
        }
    }
}

// ---------------------------------------------------------------------------
// epilogue: out[r] = x[s] + cnt[s-1] * Tb[inv[s-1]]
// ---------------------------------------------------------------------------
__global__ __launch_bounds__(256) void out_kernel(const float* __restrict__ X,
                                                  const ushort* __restrict__ Tb,
                                                  const int* __restrict__ sav,
                                                  const int* __restrict__ cnt,
                                                  const int* __restrict__ inv,
                                                  float* __restrict__ out) {
    int r = blockIdx.x;
    int d = threadIdx.x;                 // float4 lane, 0..255
    int s = sav[r];
    const float4* xr = (const float4*)(X + (size_t)s * DM);
    float4 v = xr[d];
    if (s > 0) {
        int t = s - 1;
        int c = cnt[t];
        if (c > 0) {
            float fc = (float)c;
            const ushort4* tr = (const ushort4*)(Tb + (size_t)inv[t] * DM);
            ushort4 wv = tr[d];
            v.x += fc * bf2f(wv.x); v.y += fc * bf2f(wv.y);
            v.z += fc * bf2f(wv.z); v.w += fc * bf2f(wv.w);
        }
    }
    ((float4*)out)[(size_t)r * (DM / 4) + d] = v;
}

// ---------------------------------------------------------------------------
extern "C" void kernel_launch(void* const* d_in, const int* in_sizes, int n_in,
                              void* d_out, int out_size, void* d_ws, size_t ws_size,
                              hipStream_t stream) {
    const float* X   = (const float*)d_in[0];
    const float* W   = (const float*)d_in[1];
    const int*   sav = (const int*)d_in[2];   // ids_to_save
    const int*   red = (const int*)d_in[3];   // ids_to_reduce
    float* out = (float*)d_out;

    char* ws = (char*)d_ws;
    int* counter = (int*)ws;                  // 64 ints
    int* cnt  = counter + 64;                 // 32768
    int* need = cnt + NTOK;                   // 32768
    int* inv  = need + NTOK;                  // 32768
    int* list = inv + NTOK;                   // 16384  (ends < 512 KB)
    ushort* Wb = (ushort*)(ws + (1 << 19));   // 2 MB bf16 W
    ushort* Xb = (ushort*)(ws + (4 << 20));   // 32 MB bf16 compacted X rows (padded)
    ushort* Tb = (ushort*)(ws + (36u << 20)); // 32 MB bf16 T

    setup_kernel<<<DM * DM / 4 / 256, 256, 0, stream>>>(W, Wb, cnt, need, counter);
    prep_kernel<<<NRED / 256, 256, 0, stream>>>(red, sav, cnt, need);
    compact_kernel<<<NTOK / 256, 256, 0, stream>>>(cnt, need, inv, list, counter);
    convx_kernel<<<2048, 256, 0, stream>>>(X, list, counter, Xb);

    dim3 ggrid(MMAX / 128, DM / 128);         // x = m-blocks (128, early-exit), y = n (8)
    gemm_kernel<<<ggrid, 256, 0, stream>>>(Xb, Wb, counter, Tb);

    out_kernel<<<NSAVE, 256, 0, stream>>>(X, Tb, sav, cnt, inv, out);
}

// Round 13
// 75.038 us; speedup vs baseline: 1.0330x; 1.0272x over previous
//
#include <hip/hip_runtime.h>

#define DM    1024
#define NTOK  32768   // B*S
#define NRED  16384
#define NSAVE 16384
#define MMAX  16384   // max compacted rows

typedef __attribute__((ext_vector_type(8))) short bf16x8;
typedef __attribute__((ext_vector_type(4))) float f32x4;

__device__ __forceinline__ ushort f2bf(float f) {
    union { float f; unsigned u; } v; v.f = f;
    unsigned r = (v.u + 0x7FFF + ((v.u >> 16) & 1)) >> 16;   // RNE
    return (ushort)r;
}
__device__ __forceinline__ float bf2f(ushort u) {
    union { unsigned u; float f; } v; v.u = ((unsigned)u) << 16;
    return v.f;
}

// ---------------------------------------------------------------------------
__global__ __launch_bounds__(256) void setup_kernel(const float* __restrict__ W,
                                                    ushort* __restrict__ Wb,
                                                    int* __restrict__ cnt,
                                                    int* __restrict__ need,
                                                    int* __restrict__ counter) {
    int t = blockIdx.x * 256 + threadIdx.x;
    float4 v = ((const float4*)W)[t];
    ushort4 o;
    o.x = f2bf(v.x); o.y = f2bf(v.y); o.z = f2bf(v.z); o.w = f2bf(v.w);
    ((ushort4*)Wb)[t] = o;
    if (t < NTOK) { cnt[t] = 0; need[t] = 0; }
    if (t == 0) *counter = 0;
}

// ---------------------------------------------------------------------------
__global__ __launch_bounds__(256) void prep_kernel(const int* __restrict__ red,
                                                   const int* __restrict__ sav,
                                                   int* __restrict__ cnt,
                                                   int* __restrict__ need) {
    int j = blockIdx.x * 256 + threadIdx.x;
    if (j >= NRED) return;
    atomicAdd(&cnt[red[j]], 1);
    int s = sav[j];
    if (s > 0) need[s - 1] = 1;
}

// ---------------------------------------------------------------------------
__global__ __launch_bounds__(256) void compact_kernel(const int* __restrict__ cnt,
                                                      const int* __restrict__ need,
                                                      int* __restrict__ inv,
                                                      int* __restrict__ list,
                                                      int* __restrict__ counter) {
    int t = blockIdx.x * 256 + threadIdx.x;
    if (t >= NTOK) return;
    if (need[t] && cnt[t] > 0) {
        int pos = atomicAdd(counter, 1);
        inv[t] = pos;
        list[pos] = t;
    }
}

// ---------------------------------------------------------------------------
// convx: gather + fp32->bf16 convert compacted rows; zero-pad to 128 multiple
// ---------------------------------------------------------------------------
__global__ __launch_bounds__(256) void convx_kernel(const float* __restrict__ X,
                                                    const int* __restrict__ list,
                                                    const int* __restrict__ counter,
                                                    ushort* __restrict__ Xb) {
    const int M = *counter;
    const int Mpad = (M + 127) & ~127;
    for (int r = blockIdx.x; r < Mpad; r += gridDim.x) {
        ushort4 o;
        if (r < M) {
            int src = list[r];
            float4 v = ((const float4*)(X + (size_t)src * DM))[threadIdx.x];
            o.x = f2bf(v.x); o.y = f2bf(v.y); o.z = f2bf(v.z); o.w = f2bf(v.w);
        } else {
            o.x = 0; o.y = 0; o.z = 0; o.w = 0;
        }
        ((ushort4*)(Xb + (size_t)r * DM))[threadIdx.x] = o;
    }
}

// ---------------------------------------------------------------------------
// bf16 MFMA GEMM, FAT K-STEPS: Tb[m,n] = bf16( sum_k Xb[m,k]*Wb[n,k] )
// BM=BN=128, BK=128 -> only 8 K-steps. Rationale (R7-R12 post-mortems +
// m233): the 2-phase loop has a ~2000-cyc FIXED stage/vmcnt/barrier cost
// per step; 32 thin steps = ~64k cyc of pure overhead. 8 fat steps amortize
// it 4x, and the ~1900-cyc compute phase itself hides the L2 latency of the
// depth-1 prefetch (vmcnt(16) waits on loads issued one full step earlier).
// LDS: 2 bufs x 64 KB = 128 KB (dynamic), 1 wg/CU. BK=128 stored as TWO
// 64-col halves, each with R7's validated layout: rows 128 B = 8 x 16B
// chunks, stored chunk = logical ^ (row&7) via pre-swizzled gload source
// (rule #21); all fragment rows have row&7 == r16&7 -> measured-0-conflict
// ds_read_b128 (R7). 4 waves; wave w owns m-rows [w*32,w*32+32) x 128 n:
// per step 16 gload_lds + 40 ds_read_b128 + 64 MFMA (2 fm x 8 fn x 4 kk).
// ---------------------------------------------------------------------------
__global__ __launch_bounds__(256) void gemm_kernel(const ushort* __restrict__ Xb,
                                                   const ushort* __restrict__ Wb,
                                                   const int* __restrict__ counter,
                                                   ushort* __restrict__ Tb) {
    const int M = *counter;
    const int m0 = blockIdx.x * 128;
    if (m0 >= M) return;                 // uniform exit before any barrier
    const int n0 = blockIdx.y * 128;

    extern __shared__ char lds[];        // 131072 B = 2 bufs x 64 KB
    // buf layout: A half0 [0,16K) | A half1 [16K,32K) | B half0 [32K,48K) | B half1 [48K,64K)

    const int tid = threadIdx.x;
    const int l   = tid & 63;
    const int w   = tid >> 6;            // 0..3

    // staging: wave w covers rows [w*32, w*32+32) of A and B in each half.
    // instr (h,i) covers rows w*32+i*8..+8 of half h; lane: row += l>>3,
    // stored 16B slot l&7; logical chunk = (l&7)^(row&7), row&7=(l>>3)&7.
    const int srow   = l >> 3;
    const int schunk = (l & 7) ^ (srow & 7);
    const ushort* aS = Xb + (size_t)(m0 + w * 32 + srow) * DM + schunk * 8;
    const ushort* bS = Wb + (size_t)(n0 + w * 32 + srow) * DM + schunk * 8;
    const int dOff = w * 4096;           // wave's 32-row band within a half

#define STAGE(buf, kstep) do {                                                        \
    char* _d = lds + (buf) * 65536 + dOff;                                            \
    const int _k = (kstep) * 128;                                                     \
    _Pragma("unroll")                                                                 \
    for (int _h = 0; _h < 2; ++_h)                                                    \
        _Pragma("unroll")                                                             \
        for (int _i = 0; _i < 4; ++_i) {                                              \
            __builtin_amdgcn_global_load_lds(                                         \
                (const __attribute__((address_space(1))) unsigned*)(aS + _k + _h * 64 + _i * 8 * DM), \
                (__attribute__((address_space(3))) unsigned*)(_d + _h * 16384 + _i * 1024), 16, 0, 0); \
            __builtin_amdgcn_global_load_lds(                                         \
                (const __attribute__((address_space(1))) unsigned*)(bS + _k + _h * 64 + _i * 8 * DM), \
                (__attribute__((address_space(3))) unsigned*)(_d + 32768 + _h * 16384 + _i * 1024), 16, 0, 0); \
        }                                                                             \
} while (0)

    // fragment read byte-offsets: half = kk>>1, chunk c = (kk&1)*4 + kgrp,
    // swizzled c' = c ^ (r16&7); row offset within half = row*128.
    const int kgrp = l >> 4;
    const int r16  = l & 15;
    int aoff[2][4], boff[8][4];
#pragma unroll
    for (int fm = 0; fm < 2; ++fm) {
        int row = w * 32 + fm * 16 + r16;
#pragma unroll
        for (int kk = 0; kk < 4; ++kk)
            aoff[fm][kk] = (kk >> 1) * 16384 + row * 128
                         + ((((kk & 1) * 4 + kgrp) ^ (r16 & 7)) * 16);
    }
#pragma unroll
    for (int fn = 0; fn < 8; ++fn) {
        int row = fn * 16 + r16;
#pragma unroll
        for (int kk = 0; kk < 4; ++kk)
            boff[fn][kk] = 32768 + (kk >> 1) * 16384 + row * 128
                         + ((((kk & 1) * 4 + kgrp) ^ (r16 & 7)) * 16);
    }

    f32x4 acc[2][8] = {};

    STAGE(0, 0);
#pragma unroll
    for (int t = 0; t < 8; ++t) {
        const char* base = lds + (t & 1) * 65536;
        if (t < 7) {
            STAGE((t & 1) ^ 1, t + 1);
            asm volatile("s_waitcnt vmcnt(16)" ::: "memory");  // my cur-buf 16 loads landed
        } else {
            asm volatile("s_waitcnt vmcnt(0)" ::: "memory");
        }
        __builtin_amdgcn_sched_barrier(0);
        __builtin_amdgcn_s_barrier();                          // landed for ALL waves

#pragma unroll
        for (int kk = 0; kk < 4; ++kk) {
            bf16x8 af[2], bfr[8];
#pragma unroll
            for (int fm = 0; fm < 2; ++fm) af[fm]  = *(const bf16x8*)(base + aoff[fm][kk]);
#pragma unroll
            for (int fn = 0; fn < 8; ++fn) bfr[fn] = *(const bf16x8*)(base + boff[fn][kk]);
#pragma unroll
            for (int fm = 0; fm < 2; ++fm)
#pragma unroll
                for (int fn = 0; fn < 8; ++fn)
                    acc[fm][fn] = __builtin_amdgcn_mfma_f32_16x16x32_bf16(af[fm], bfr[fn], acc[fm][fn], 0, 0, 0);
        }

        if (t < 7)
            __builtin_amdgcn_s_barrier();   // all reads of cur buf done; t+1 may overwrite it
    }
#undef STAGE

    // C/D layout: col = lane&15, row = (lane>>4)*4 + reg  [m89]
#pragma unroll
    for (int fm = 0; fm < 2; ++fm) {
        int mbase = m0 + w * 32 + fm * 16 + kgrp * 4;
#pragma unroll
        for (int fn = 0; fn < 8; ++fn) {
            int n = n0 + fn * 16 + r16;
#pragma unroll
            for (int r = 0; r < 4; ++r) {
                int m = mbase + r;
                if (m < M) Tb[(size_t)m * DM + n] = f2bf(acc[fm][fn][r]);
            }
        }
    }
}

// ---------------------------------------------------------------------------
// epilogue: out[r] = x[s] + cnt[s-1] * Tb[inv[s-1]]
// ---------------------------------------------------------------------------
__global__ __launch_bounds__(256) void out_kernel(const float* __restrict__ X,
                                                  const ushort* __restrict__ Tb,
                                                  const int* __restrict__ sav,
                                                  const int* __restrict__ cnt,
                                                  const int* __restrict__ inv,
                                                  float* __restrict__ out) {
    int r = blockIdx.x;
    int d = threadIdx.x;                 // float4 lane, 0..255
    int s = sav[r];
    const float4* xr = (const float4*)(X + (size_t)s * DM);
    float4 v = xr[d];
    if (s > 0) {
        int t = s - 1;
        int c = cnt[t];
        if (c > 0) {
            float fc = (float)c;
            const ushort4* tr = (const ushort4*)(Tb + (size_t)inv[t] * DM);
            ushort4 wv = tr[d];
            v.x += fc * bf2f(wv.x); v.y += fc * bf2f(wv.y);
            v.z += fc * bf2f(wv.z); v.w += fc * bf2f(wv.w);
        }
    }
    ((float4*)out)[(size_t)r * (DM / 4) + d] = v;
}

// ---------------------------------------------------------------------------
extern "C" void kernel_launch(void* const* d_in, const int* in_sizes, int n_in,
                              void* d_out, int out_size, void* d_ws, size_t ws_size,
                              hipStream_t stream) {
    const float* X   = (const float*)d_in[0];
    const float* W   = (const float*)d_in[1];
    const int*   sav = (const int*)d_in[2];   // ids_to_save
    const int*   red = (const int*)d_in[3];   // ids_to_reduce
    float* out = (float*)d_out;

    char* ws = (char*)d_ws;
    int* counter = (int*)ws;                  // 64 ints
    int* cnt  = counter + 64;                 // 32768
    int* need = cnt + NTOK;                   // 32768
    int* inv  = need + NTOK;                  // 32768
    int* list = inv + NTOK;                   // 16384  (ends < 512 KB)
    ushort* Wb = (ushort*)(ws + (1 << 19));   // 2 MB bf16 W
    ushort* Xb = (ushort*)(ws + (4 << 20));   // 32 MB bf16 compacted X rows (padded)
    ushort* Tb = (ushort*)(ws + (36u << 20)); // 32 MB bf16 T

    setup_kernel<<<DM * DM / 4 / 256, 256, 0, stream>>>(W, Wb, cnt, need, counter);
    prep_kernel<<<NRED / 256, 256, 0, stream>>>(red, sav, cnt, need);
    compact_kernel<<<NTOK / 256, 256, 0, stream>>>(cnt, need, inv, list, counter);
    convx_kernel<<<2048, 256, 0, stream>>>(X, list, counter, Xb);

    dim3 ggrid(MMAX / 128, DM / 128);         // x = m-blocks (128, early-exit), y = n (8)
    gemm_kernel<<<ggrid, 256, 131072, stream>>>(Xb, Wb, counter, Tb);

    out_kernel<<<NSAVE, 256, 0, stream>>>(X, Tb, sav, cnt, inv, out);
}

// Round 14
// 71.142 us; speedup vs baseline: 1.0896x; 1.0548x over previous
//
#include <hip/hip_runtime.h>

#define DM    1024
#define NTOK  32768   // B*S
#define NRED  16384
#define NSAVE 16384
#define MMAX  16384   // max compacted rows

typedef __attribute__((ext_vector_type(8))) short bf16x8;
typedef __attribute__((ext_vector_type(4))) float f32x4;

__device__ __forceinline__ ushort f2bf(float f) {
    union { float f; unsigned u; } v; v.f = f;
    unsigned r = (v.u + 0x7FFF + ((v.u >> 16) & 1)) >> 16;   // RNE
    return (ushort)r;
}
__device__ __forceinline__ float bf2f(ushort u) {
    union { unsigned u; float f; } v; v.u = ((unsigned)u) << 16;
    return v.f;
}

// ---------------------------------------------------------------------------
__global__ __launch_bounds__(256) void setup_kernel(const float* __restrict__ W,
                                                    ushort* __restrict__ Wb,
                                                    int* __restrict__ cnt,
                                                    int* __restrict__ need,
                                                    int* __restrict__ counter) {
    int t = blockIdx.x * 256 + threadIdx.x;
    float4 v = ((const float4*)W)[t];
    ushort4 o;
    o.x = f2bf(v.x); o.y = f2bf(v.y); o.z = f2bf(v.z); o.w = f2bf(v.w);
    ((ushort4*)Wb)[t] = o;
    if (t < NTOK) { cnt[t] = 0; need[t] = 0; }
    if (t == 0) *counter = 0;
}

// ---------------------------------------------------------------------------
__global__ __launch_bounds__(256) void prep_kernel(const int* __restrict__ red,
                                                   const int* __restrict__ sav,
                                                   int* __restrict__ cnt,
                                                   int* __restrict__ need) {
    int j = blockIdx.x * 256 + threadIdx.x;
    if (j >= NRED) return;
    atomicAdd(&cnt[red[j]], 1);
    int s = sav[j];
    if (s > 0) need[s - 1] = 1;
}

// ---------------------------------------------------------------------------
__global__ __launch_bounds__(256) void compact_kernel(const int* __restrict__ cnt,
                                                      const int* __restrict__ need,
                                                      int* __restrict__ inv,
                                                      int* __restrict__ list,
                                                      int* __restrict__ counter) {
    int t = blockIdx.x * 256 + threadIdx.x;
    if (t >= NTOK) return;
    if (need[t] && cnt[t] > 0) {
        int pos = atomicAdd(counter, 1);
        inv[t] = pos;
        list[pos] = t;
    }
}

// ---------------------------------------------------------------------------
// convx: gather + fp32->bf16 convert compacted rows; zero-pad to 128 multiple
// ---------------------------------------------------------------------------
__global__ __launch_bounds__(256) void convx_kernel(const float* __restrict__ X,
                                                    const int* __restrict__ list,
                                                    const int* __restrict__ counter,
                                                    ushort* __restrict__ Xb) {
    const int M = *counter;
    const int Mpad = (M + 127) & ~127;
    for (int r = blockIdx.x; r < Mpad; r += gridDim.x) {
        ushort4 o;
        if (r < M) {
            int src = list[r];
            float4 v = ((const float4*)(X + (size_t)src * DM))[threadIdx.x];
            o.x = f2bf(v.x); o.y = f2bf(v.y); o.z = f2bf(v.z); o.w = f2bf(v.w);
        } else {
            o.x = 0; o.y = 0; o.z = 0; o.w = 0;
        }
        ((ushort4*)(Xb + (size_t)r * DM))[threadIdx.x] = o;
    }
}

// ---------------------------------------------------------------------------
// bf16 MFMA GEMM (R7 structure, best measured) + IDLE-WG OUTPUT COPY.
// Active wgs (m0 < M): Tb[m,n] = bf16( sum_k Xb[m,k]*Wb[n,k] ), BM=BN=128,
// BK=64, 4 waves, depth-1 counted vmcnt(8) + raw barriers, pre-swizzled
// gload_lds staging (rule #21, 0 bank conflicts measured R7).
// Idle wgs (m0 >= M; ~704 of 1024): grid-stride copy of INDEPENDENT output
// rows (s==0 or cnt[s-1]==0): out[r] = x[s]. The GEMM is latency-bound at
// <10% HBM (R6 counters), so this ~80 MB copy rides on idle CU slots and
// idle HBM for ~free, removing it from the serial out pass.
// ---------------------------------------------------------------------------
__global__ __launch_bounds__(256) void gemm_kernel(const ushort* __restrict__ Xb,
                                                   const ushort* __restrict__ Wb,
                                                   const int* __restrict__ counter,
                                                   ushort* __restrict__ Tb,
                                                   const float* __restrict__ X,
                                                   const int* __restrict__ sav,
                                                   const int* __restrict__ cnt,
                                                   float* __restrict__ out) {
    const int M = *counter;
    const int m0 = blockIdx.x * 128;
    const int tid = threadIdx.x;

    if (m0 >= M) {
        // ---- idle wg: copy independent output rows ----
        const int nAct  = (M + 127) >> 7;
        const int idleId = (blockIdx.x - nAct) * gridDim.y + blockIdx.y;
        const int nIdle  = (gridDim.x - nAct) * gridDim.y;
        for (int r = idleId; r < NSAVE; r += nIdle) {
            int s = sav[r];
            if (s > 0 && cnt[s - 1] > 0) continue;   // dependent: out_dep writes it
            ((float4*)out)[(size_t)r * 256 + tid] =
                ((const float4*)(X + (size_t)s * DM))[tid];
        }
        return;
    }

    const int n0 = blockIdx.y * 128;

    __shared__ char lds[65536];          // 2 bufs x (A 16KB + B 16KB)

    const int l = tid & 63;
    const int w = tid >> 6;

    // staging: wave w covers rows [w*32, w*32+32) of A and B; instr i covers
    // 8 rows; lane: row = w*32 + i*8 + (l>>3), stored slot l&7, logical chunk
    // = (l&7)^(row&7); row&7 == (l>>3)&7 independent of i,w.
    const int srow   = l >> 3;
    const int schunk = (l & 7) ^ (srow & 7);
    const ushort* aS = Xb + (size_t)(m0 + w * 32 + srow) * DM + schunk * 8;
    const ushort* bS = Wb + (size_t)(n0 + w * 32 + srow) * DM + schunk * 8;
    const int dOff = w * 4096;

#define STAGE(buf, k0) do {                                                          \
    char* _a = lds + (buf) * 32768 + dOff;                                           \
    _Pragma("unroll")                                                                \
    for (int _i = 0; _i < 4; ++_i) {                                                 \
        __builtin_amdgcn_global_load_lds(                                            \
            (const __attribute__((address_space(1))) unsigned*)(aS + (k0) + _i * 8 * DM), \
            (__attribute__((address_space(3))) unsigned*)(_a + _i * 1024), 16, 0, 0);      \
        __builtin_amdgcn_global_load_lds(                                            \
            (const __attribute__((address_space(1))) unsigned*)(bS + (k0) + _i * 8 * DM), \
            (__attribute__((address_space(3))) unsigned*)(_a + 16384 + _i * 1024), 16, 0, 0); \
    }                                                                                \
} while (0)

    const int kgrp = l >> 4;
    const int r16  = l & 15;
    int aoff[2][2], boff[8][2];
#pragma unroll
    for (int fm = 0; fm < 2; ++fm) {
        int row = w * 32 + fm * 16 + r16;
#pragma unroll
        for (int kk = 0; kk < 2; ++kk)
            aoff[fm][kk] = row * 128 + (((kk * 4 + kgrp) ^ (row & 7)) * 16);
    }
#pragma unroll
    for (int fn = 0; fn < 8; ++fn) {
        int row = fn * 16 + r16;
#pragma unroll
        for (int kk = 0; kk < 2; ++kk)
            boff[fn][kk] = 16384 + row * 128 + (((kk * 4 + kgrp) ^ (row & 7)) * 16);
    }

    f32x4 acc[2][8] = {};

    STAGE(0, 0);
#pragma unroll
    for (int t = 0; t < 16; ++t) {
        const char* base = lds + (t & 1) * 32768;
        if (t < 15) {
            STAGE((t & 1) ^ 1, (t + 1) * 64);
            asm volatile("s_waitcnt vmcnt(8)" ::: "memory");   // my cur-buf loads landed
        } else {
            asm volatile("s_waitcnt vmcnt(0)" ::: "memory");
        }
        __builtin_amdgcn_sched_barrier(0);
        __builtin_amdgcn_s_barrier();                          // everyone's cur loads landed

#pragma unroll
        for (int kk = 0; kk < 2; ++kk) {
            bf16x8 af[2], bfr[8];
#pragma unroll
            for (int fm = 0; fm < 2; ++fm) af[fm]  = *(const bf16x8*)(base + aoff[fm][kk]);
#pragma unroll
            for (int fn = 0; fn < 8; ++fn) bfr[fn] = *(const bf16x8*)(base + boff[fn][kk]);
#pragma unroll
            for (int fm = 0; fm < 2; ++fm)
#pragma unroll
                for (int fn = 0; fn < 8; ++fn)
                    acc[fm][fn] = __builtin_amdgcn_mfma_f32_16x16x32_bf16(af[fm], bfr[fn], acc[fm][fn], 0, 0, 0);
        }

        if (t < 15)
            __builtin_amdgcn_s_barrier();   // all reads of cur done -> next STAGE may overwrite
    }
#undef STAGE

    // C/D layout: col = lane&15, row = (lane>>4)*4 + reg  [m89]
#pragma unroll
    for (int fm = 0; fm < 2; ++fm) {
        int mbase = m0 + w * 32 + fm * 16 + kgrp * 4;
#pragma unroll
        for (int fn = 0; fn < 8; ++fn) {
            int n = n0 + fn * 16 + r16;
#pragma unroll
            for (int r = 0; r < 4; ++r) {
                int m = mbase + r;
                if (m < M) Tb[(size_t)m * DM + n] = f2bf(acc[fm][fn][r]);
            }
        }
    }
}

// ---------------------------------------------------------------------------
// out_dep: dependent rows only: out[r] = x[s] + cnt[s-1] * Tb[inv[s-1]]
// (independent rows were written by the gemm kernel's idle wgs)
// ---------------------------------------------------------------------------
__global__ __launch_bounds__(256) void out_dep_kernel(const float* __restrict__ X,
                                                      const ushort* __restrict__ Tb,
                                                      const int* __restrict__ sav,
                                                      const int* __restrict__ cnt,
                                                      const int* __restrict__ inv,
                                                      float* __restrict__ out) {
    int r = blockIdx.x;
    int s = sav[r];
    if (s == 0) return;
    int c = cnt[s - 1];
    if (c == 0) return;
    int d = threadIdx.x;                 // float4 lane, 0..255
    float fc = (float)c;
    float4 v = ((const float4*)(X + (size_t)s * DM))[d];
    ushort4 wv = ((const ushort4*)(Tb + (size_t)inv[s - 1] * DM))[d];
    v.x += fc * bf2f(wv.x); v.y += fc * bf2f(wv.y);
    v.z += fc * bf2f(wv.z); v.w += fc * bf2f(wv.w);
    ((float4*)out)[(size_t)r * 256 + d] = v;
}

// ---------------------------------------------------------------------------
extern "C" void kernel_launch(void* const* d_in, const int* in_sizes, int n_in,
                              void* d_out, int out_size, void* d_ws, size_t ws_size,
                              hipStream_t stream) {
    const float* X   = (const float*)d_in[0];
    const float* W   = (const float*)d_in[1];
    const int*   sav = (const int*)d_in[2];   // ids_to_save
    const int*   red = (const int*)d_in[3];   // ids_to_reduce
    float* out = (float*)d_out;

    char* ws = (char*)d_ws;
    int* counter = (int*)ws;                  // 64 ints
    int* cnt  = counter + 64;                 // 32768
    int* need = cnt + NTOK;                   // 32768
    int* inv  = need + NTOK;                  // 32768
    int* list = inv + NTOK;                   // 16384  (ends < 512 KB)
    ushort* Wb = (ushort*)(ws + (1 << 19));   // 2 MB bf16 W
    ushort* Xb = (ushort*)(ws + (4 << 20));   // 32 MB bf16 compacted X rows (padded)
    ushort* Tb = (ushort*)(ws + (36u << 20)); // 32 MB bf16 T

    setup_kernel<<<DM * DM / 4 / 256, 256, 0, stream>>>(W, Wb, cnt, need, counter);
    prep_kernel<<<NRED / 256, 256, 0, stream>>>(red, sav, cnt, need);
    compact_kernel<<<NTOK / 256, 256, 0, stream>>>(cnt, need, inv, list, counter);
    convx_kernel<<<2048, 256, 0, stream>>>(X, list, counter, Xb);

    dim3 ggrid(MMAX / 128, DM / 128);         // 128 x-blocks (idle ones copy), 8 n-blocks
    gemm_kernel<<<ggrid, 256, 0, stream>>>(Xb, Wb, counter, Tb, X, sav, cnt, out);

    out_dep_kernel<<<NSAVE, 256, 0, stream>>>(X, Tb, sav, cnt, inv, out);
}

// Round 16
// 68.895 us; speedup vs baseline: 1.1251x; 1.0326x over previous
//
#include <hip/hip_runtime.h>

#define DM    1024
#define NTOK  32768   // B*S
#define NRED  16384
#define NSAVE 16384
#define MMAX  16384   // max compacted rows

typedef __attribute__((ext_vector_type(8))) short bf16x8;
typedef __attribute__((ext_vector_type(4))) float f32x4;

__device__ __forceinline__ ushort f2bf(float f) {
    union { float f; unsigned u; } v; v.f = f;
    unsigned r = (v.u + 0x7FFF + ((v.u >> 16) & 1)) >> 16;   // RNE
    return (ushort)r;
}
__device__ __forceinline__ float bf2f(ushort u) {
    union { unsigned u; float f; } v; v.u = ((unsigned)u) << 16;
    return v.f;
}

// ---------------------------------------------------------------------------
__global__ __launch_bounds__(256) void setup_kernel(const float* __restrict__ W,
                                                    ushort* __restrict__ Wb,
                                                    int* __restrict__ cnt,
                                                    int* __restrict__ need,
                                                    int* __restrict__ counter) {
    int t = blockIdx.x * 256 + threadIdx.x;
    float4 v = ((const float4*)W)[t];
    ushort4 o;
    o.x = f2bf(v.x); o.y = f2bf(v.y); o.z = f2bf(v.z); o.w = f2bf(v.w);
    ((ushort4*)Wb)[t] = o;
    if (t < NTOK) { cnt[t] = 0; need[t] = 0; }
    if (t == 0) *counter = 0;
}

// ---------------------------------------------------------------------------
__global__ __launch_bounds__(256) void prep_kernel(const int* __restrict__ red,
                                                   const int* __restrict__ sav,
                                                   int* __restrict__ cnt,
                                                   int* __restrict__ need) {
    int j = blockIdx.x * 256 + threadIdx.x;
    if (j >= NRED) return;
    atomicAdd(&cnt[red[j]], 1);
    int s = sav[j];
    if (s > 0) need[s - 1] = 1;
}

// ---------------------------------------------------------------------------
__global__ __launch_bounds__(256) void compact_kernel(const int* __restrict__ cnt,
                                                      const int* __restrict__ need,
                                                      int* __restrict__ inv,
                                                      int* __restrict__ list,
                                                      int* __restrict__ counter) {
    int t = blockIdx.x * 256 + threadIdx.x;
    if (t >= NTOK) return;
    if (need[t] && cnt[t] > 0) {
        int pos = atomicAdd(counter, 1);
        inv[t] = pos;
        list[pos] = t;
    }
}

// ---------------------------------------------------------------------------
// convx: gather + fp32->bf16 convert compacted rows; zero-pad to 128 multiple
// ---------------------------------------------------------------------------
__global__ __launch_bounds__(256) void convx_kernel(const float* __restrict__ X,
                                                    const int* __restrict__ list,
                                                    const int* __restrict__ counter,
                                                    ushort* __restrict__ Xb) {
    const int M = *counter;
    const int Mpad = (M + 127) & ~127;
    for (int r = blockIdx.x; r < Mpad; r += gridDim.x) {
        ushort4 o;
        if (r < M) {
            int src = list[r];
            float4 v = ((const float4*)(X + (size_t)src * DM))[threadIdx.x];
            o.x = f2bf(v.x); o.y = f2bf(v.y); o.z = f2bf(v.z); o.w = f2bf(v.w);
        } else {
            o.x = 0; o.y = 0; o.z = 0; o.w = 0;
        }
        ((ushort4*)(Xb + (size_t)r * DM))[threadIdx.x] = o;
    }
}

// ---------------------------------------------------------------------------
// bf16 MFMA GEMM: R7 structure (best measured: 67.3 total), PARAMETER CHANGE
// ONLY: BN 128 -> 64. Grid 40x16 = 640 active wgs (2x R7), LDS 48 KB -> 3
// wg/CU = 12 waves/CU (vs R7's 2/8). The per-step fixed stage/vmcnt/barrier
// overhead (m233: ~72% of 2-phase step time) now overlaps across 3
// independent wgs per CU (m114). Sync structure, swizzle (rule #21), and
// barrier placement IDENTICAL to R7 (verified: passed, 0 bank conflicts).
// Per wave-step: 6 gload_lds (vmcnt(6) counted), 12 ds_read_b128, 16 MFMA.
// BM=128, BN=64, BK=64, 4 waves; wave w stages A rows [w*32,+32), B rows
// [w*16,+16); computes m-band [w*32,+32) x all 64 n (2x4 frags 16x16x32).
// ---------------------------------------------------------------------------
__global__ __launch_bounds__(256) void gemm_kernel(const ushort* __restrict__ Xb,
                                                   const ushort* __restrict__ Wb,
                                                   const int* __restrict__ counter,
                                                   ushort* __restrict__ Tb) {
    const int M = *counter;
    const int m0 = blockIdx.x * 128;
    if (m0 >= M) return;                 // uniform exit before any barrier
    const int n0 = blockIdx.y * 64;

    __shared__ char lds[49152];          // 2 bufs x (A 16KB + B 8KB)

    const int tid = threadIdx.x;
    const int l   = tid & 63;
    const int w   = tid >> 6;

    // staging: A instr i covers rows w*32 + i*8 + (l>>3), i<4;
    //          B instr i covers rows w*16 + i*8 + (l>>3), i<2.
    // stored 16B slot l&7; logical chunk = (l&7)^(row&7); row&7 == (l>>3)&7.
    const int srow   = l >> 3;
    const int schunk = (l & 7) ^ (srow & 7);
    const ushort* aS = Xb + (size_t)(m0 + w * 32 + srow) * DM + schunk * 8;
    const ushort* bS = Wb + (size_t)(n0 + w * 16 + srow) * DM + schunk * 8;
    const int dOffA = w * 4096;          // 32 rows x 128 B
    const int dOffB = 16384 + w * 2048;  // B region starts at 16 KB; 16 rows x 128 B

#define STAGE(buf, k0) do {                                                          \
    char* _a = lds + (buf) * 24576 + dOffA;                                          \
    char* _b = lds + (buf) * 24576 + dOffB;                                          \
    _Pragma("unroll")                                                                \
    for (int _i = 0; _i < 4; ++_i)                                                   \
        __builtin_amdgcn_global_load_lds(                                            \
            (const __attribute__((address_space(1))) unsigned*)(aS + (k0) + _i * 8 * DM), \
            (__attribute__((address_space(3))) unsigned*)(_a + _i * 1024), 16, 0, 0);      \
    _Pragma("unroll")                                                                \
    for (int _i = 0; _i < 2; ++_i)                                                   \
        __builtin_amdgcn_global_load_lds(                                            \
            (const __attribute__((address_space(1))) unsigned*)(bS + (k0) + _i * 8 * DM), \
            (__attribute__((address_space(3))) unsigned*)(_b + _i * 1024), 16, 0, 0);      \
} while (0)

    // fragment read byte-offsets within a buffer (same swizzle as staging)
    const int kgrp = l >> 4;
    const int r16  = l & 15;
    int aoff[2][2], boff[4][2];
#pragma unroll
    for (int fm = 0; fm < 2; ++fm) {
        int row = w * 32 + fm * 16 + r16;
#pragma unroll
        for (int kk = 0; kk < 2; ++kk)
            aoff[fm][kk] = row * 128 + (((kk * 4 + kgrp) ^ (row & 7)) * 16);
    }
#pragma unroll
    for (int fn = 0; fn < 4; ++fn) {
        int row = fn * 16 + r16;
#pragma unroll
        for (int kk = 0; kk < 2; ++kk)
            boff[fn][kk] = 16384 + row * 128 + (((kk * 4 + kgrp) ^ (row & 7)) * 16);
    }

    f32x4 acc[2][4] = {};

    STAGE(0, 0);
#pragma unroll
    for (int t = 0; t < 16; ++t) {
        const char* base = lds + (t & 1) * 24576;
        if (t < 15) {
            STAGE((t & 1) ^ 1, (t + 1) * 64);
            asm volatile("s_waitcnt vmcnt(6)" ::: "memory");   // my cur-buf 6 loads landed
        } else {
            asm volatile("s_waitcnt vmcnt(0)" ::: "memory");
        }
        __builtin_amdgcn_sched_barrier(0);
        __builtin_amdgcn_s_barrier();                          // everyone's cur loads landed

#pragma unroll
        for (int kk = 0; kk < 2; ++kk) {
            bf16x8 af[2], bfr[4];
#pragma unroll
            for (int fm = 0; fm < 2; ++fm) af[fm]  = *(const bf16x8*)(base + aoff[fm][kk]);
#pragma unroll
            for (int fn = 0; fn < 4; ++fn) bfr[fn] = *(const bf16x8*)(base + boff[fn][kk]);
#pragma unroll
            for (int fm = 0; fm < 2; ++fm)
#pragma unroll
                for (int fn = 0; fn < 4; ++fn)
                    acc[fm][fn] = __builtin_amdgcn_mfma_f32_16x16x32_bf16(af[fm], bfr[fn], acc[fm][fn], 0, 0, 0);
        }

        if (t < 15)
            __builtin_amdgcn_s_barrier();   // all reads of cur done -> next STAGE may overwrite
    }
#undef STAGE

    // C/D layout: col = lane&15, row = (lane>>4)*4 + reg  [m89]
#pragma unroll
    for (int fm = 0; fm < 2; ++fm) {
        int mbase = m0 + w * 32 + fm * 16 + kgrp * 4;
#pragma unroll
        for (int fn = 0; fn < 4; ++fn) {
            int n = n0 + fn * 16 + r16;
#pragma unroll
            for (int r = 0; r < 4; ++r) {
                int m = mbase + r;
                if (m < M) Tb[(size_t)m * DM + n] = f2bf(acc[fm][fn][r]);
            }
        }
    }
}

// ---------------------------------------------------------------------------
// epilogue: out[r] = x[s] + cnt[s-1] * Tb[inv[s-1]]
// ---------------------------------------------------------------------------
__global__ __launch_bounds__(256) void out_kernel(const float* __restrict__ X,
                                                  const ushort* __restrict__ Tb,
                                                  const int* __restrict__ sav,
                                                  const int* __restrict__ cnt,
                                                  const int* __restrict__ inv,
                                                  float* __restrict__ out) {
    int r = blockIdx.x;
    int d = threadIdx.x;                 // float4 lane, 0..255
    int s = sav[r];
    const float4* xr = (const float4*)(X + (size_t)s * DM);
    float4 v = xr[d];
    if (s > 0) {
        int t = s - 1;
        int c = cnt[t];
        if (c > 0) {
            float fc = (float)c;
            const ushort4* tr = (const ushort4*)(Tb + (size_t)inv[t] * DM);
            ushort4 wv = tr[d];
            v.x += fc * bf2f(wv.x); v.y += fc * bf2f(wv.y);
            v.z += fc * bf2f(wv.z); v.w += fc * bf2f(wv.w);
        }
    }
    ((float4*)out)[(size_t)r * (DM / 4) + d] = v;
}

// ---------------------------------------------------------------------------
extern "C" void kernel_launch(void* const* d_in, const int* in_sizes, int n_in,
                              void* d_out, int out_size, void* d_ws, size_t ws_size,
                              hipStream_t stream) {
    const float* X   = (const float*)d_in[0];
    const float* W   = (const float*)d_in[1];
    const int*   sav = (const int*)d_in[2];   // ids_to_save
    const int*   red = (const int*)d_in[3];   // ids_to_reduce
    float* out = (float*)d_out;

    char* ws = (char*)d_ws;
    int* counter = (int*)ws;                  // 64 ints
    int* cnt  = counter + 64;                 // 32768
    int* need = cnt + NTOK;                   // 32768
    int* inv  = need + NTOK;                  // 32768
    int* list = inv + NTOK;                   // 16384  (ends < 512 KB)
    ushort* Wb = (ushort*)(ws + (1 << 19));   // 2 MB bf16 W
    ushort* Xb = (ushort*)(ws + (4 << 20));   // 32 MB bf16 compacted X rows (padded)
    ushort* Tb = (ushort*)(ws + (36u << 20)); // 32 MB bf16 T

    setup_kernel<<<DM * DM / 4 / 256, 256, 0, stream>>>(W, Wb, cnt, need, counter);
    prep_kernel<<<NRED / 256, 256, 0, stream>>>(red, sav, cnt, need);
    compact_kernel<<<NTOK / 256, 256, 0, stream>>>(cnt, need, inv, list, counter);
    convx_kernel<<<2048, 256, 0, stream>>>(X, list, counter, Xb);

    dim3 ggrid(MMAX / 128, DM / 64);          // x = m-blocks (128, early-exit), y = n (16)
    gemm_kernel<<<ggrid, 256, 0, stream>>>(Xb, Wb, counter, Tb);

    out_kernel<<<NSAVE, 256, 0, stream>>>(X, Tb, sav, cnt, inv, out);
}